// Round 2
// baseline (98.000 us; speedup 1.0000x reference)
//
#include <hip/hip_runtime.h>

// RBF: out[b,l] = exp(-(1/256) * max(||x_b||^2 + ||l_l||^2 - 2 x_b·l_l, 0))
// B=8192, L=2048, D=256.
// R2: XOR-swizzled LDS (kill 16-lane/4-bank ds_read_b128 conflicts),
//     A/B swapped so epilogue stores are contiguous float4 (nontemporal),
//     fused cvt pre-pass, scaled norms precomputed.

typedef __bf16 bf16x8 __attribute__((ext_vector_type(8)));
typedef float  f32x4  __attribute__((ext_vector_type(4)));

#define B_ROWS 8192
#define L_ROWS 2048
#define K_DIM  256
#define NEG_GAMMA (-1.0f / 256.0f)

#define GLD_LDS(g, l) __builtin_amdgcn_global_load_lds(                      \
    (const __attribute__((address_space(1))) void*)(g),                      \
    (__attribute__((address_space(3))) void*)(l), 16, 0, 0)

__device__ __forceinline__ unsigned short f32_to_bf16_rne(float f) {
    union { float f; unsigned int u; } v; v.f = f;
    unsigned int u = v.u;
    return (unsigned short)((u + 0x7fffu + ((u >> 16) & 1u)) >> 16);
}

// One wave per 256-float row (x rows then landmark rows): bf16 convert (RNE)
// + store -gamma * ||row||^2.
__global__ __launch_bounds__(256) void cvt_rows_kernel(
    const float* __restrict__ x, const float* __restrict__ lm,
    unsigned short* __restrict__ xb, unsigned short* __restrict__ lb,
    float* __restrict__ gx2, float* __restrict__ gl2)
{
    const int lane = threadIdx.x & 63;
    const int row  = blockIdx.x * 4 + (threadIdx.x >> 6);
    const float* src; unsigned short* dst; float* nrm;
    if (row < B_ROWS) {
        src = x + (size_t)row * K_DIM; dst = xb + (size_t)row * K_DIM; nrm = gx2 + row;
    } else {
        const int r = row - B_ROWS;
        src = lm + (size_t)r * K_DIM; dst = lb + (size_t)r * K_DIM; nrm = gl2 + r;
    }
    const float4 v = ((const float4*)src)[lane];
    ushort4 o;
    o.x = f32_to_bf16_rne(v.x);
    o.y = f32_to_bf16_rne(v.y);
    o.z = f32_to_bf16_rne(v.z);
    o.w = f32_to_bf16_rne(v.w);
    ((ushort4*)dst)[lane] = o;
    float s = v.x*v.x + v.y*v.y + v.z*v.z + v.w*v.w;
    #pragma unroll
    for (int off = 32; off > 0; off >>= 1) s += __shfl_down(s, off, 64);
    if (lane == 0) nrm[0] = NEG_GAMMA * s;
}

// 128x128 tile, NT, 4 waves 2x2, each wave 64x64 via 4x4 of 16x16x32 bf16 MFMA.
// M = landmarks (2048), N = x (8192) -> C/D lane mapping gives each lane 4
// consecutive l's at fixed b => float4 stores into out[b][l].
// LDS: [128 rows][64 cols] bf16, physical col-block = logical ^ (row & 7).
__global__ __launch_bounds__(256) void rbf_gemm_kernel(
    const unsigned short* __restrict__ Lmat,  // landmarks bf16 [2048][256]
    const unsigned short* __restrict__ Xmat,  // x bf16 [8192][256]
    const float* __restrict__ gl2,            // -gamma*||l||^2 [2048]
    const float* __restrict__ gx2,            // -gamma*||x||^2 [8192]
    float* __restrict__ out)                  // [8192][2048]
{
    __shared__ unsigned short As[128 * 64];  // landmarks tile, 16 KB
    __shared__ unsigned short Bs[128 * 64];  // x tile, 16 KB

    const int tid  = threadIdx.x;
    const int wave = tid >> 6;
    const int lane = tid & 63;
    const int wm = wave >> 1, wn = wave & 1;
    const int bn = blockIdx.x;   // x tile (64)
    const int bm = blockIdx.y;   // landmark tile (16)

    f32x4 acc[4][4];
    #pragma unroll
    for (int i = 0; i < 4; ++i)
        #pragma unroll
        for (int j = 0; j < 4; ++j)
            acc[i][j] = (f32x4){0.f, 0.f, 0.f, 0.f};

    // Staging (global_load_lds is wave-uniform base + lane*16B):
    // lane l -> LDS row r + (l>>3), physical col-block (l&7).
    // XOR swizzle: fetch logical col-block (l&7) ^ (l>>3) from global so that
    // logical block c of row rr sits at physical block c ^ (rr & 7).
    const int lrow = lane >> 3;             // 0..7
    const int lblk = (lane & 7) ^ lrow;     // logical k-block fetched by this lane

    const unsigned short* Ab = Lmat + (size_t)(bm * 128) * K_DIM;
    const unsigned short* Bb = Xmat + (size_t)(bn * 128) * K_DIM;

    const int rlo = lane & 15;   // row-within-16-tile for frag reads
    const int q   = lane >> 4;   // quad

    for (int k0 = 0; k0 < K_DIM; k0 += 64) {
        #pragma unroll
        for (int it = 0; it < 4; ++it) {
            const int r = wave * 32 + it * 8;
            GLD_LDS(Ab + (size_t)(r + lrow) * K_DIM + k0 + lblk * 8, &As[r * 64]);
            GLD_LDS(Bb + (size_t)(r + lrow) * K_DIM + k0 + lblk * 8, &Bs[r * 64]);
        }
        __syncthreads();

        #pragma unroll
        for (int kk = 0; kk < 64; kk += 32) {
            const int kb = (kk >> 3) + q;            // logical k-block 0..7
            const int pb = (kb ^ (rlo & 7)) * 8;     // physical col offset (elems)
            bf16x8 af[4], bfr[4];
            #pragma unroll
            for (int t = 0; t < 4; ++t) {
                af[t]  = *(const bf16x8*)&As[(wm*64 + t*16 + rlo) * 64 + pb];
                bfr[t] = *(const bf16x8*)&Bs[(wn*64 + t*16 + rlo) * 64 + pb];
            }
            #pragma unroll
            for (int mt = 0; mt < 4; ++mt)
                #pragma unroll
                for (int nt = 0; nt < 4; ++nt)
                    acc[mt][nt] = __builtin_amdgcn_mfma_f32_16x16x32_bf16(
                        af[mt], bfr[nt], acc[mt][nt], 0, 0, 0);
        }
        __syncthreads();
    }

    // Epilogue. C/D: col(lane&15)=b within tile, row(quad*4+reg)=l within tile.
    const float twog = 2.0f / 256.0f;
    const int b0 = bn * 128 + wn * 64 + rlo;
    const int l0 = bm * 128 + wm * 64 + q * 4;
    #pragma unroll
    for (int nt = 0; nt < 4; ++nt) {
        const int b = b0 + nt * 16;
        const float gx = gx2[b];
        float* orow = out + (size_t)b * L_ROWS;
        #pragma unroll
        for (int mt = 0; mt < 4; ++mt) {
            const int l = l0 + mt * 16;
            const float4 gl = *(const float4*)&gl2[l];
            f32x4 o;
            o[0] = __expf(fminf(fmaf(twog, acc[mt][nt][0], gx + gl.x), 0.f));
            o[1] = __expf(fminf(fmaf(twog, acc[mt][nt][1], gx + gl.y), 0.f));
            o[2] = __expf(fminf(fmaf(twog, acc[mt][nt][2], gx + gl.z), 0.f));
            o[3] = __expf(fminf(fmaf(twog, acc[mt][nt][3], gx + gl.w), 0.f));
            __builtin_nontemporal_store(o, (f32x4*)&orow[l]);
        }
    }
}

extern "C" void kernel_launch(void* const* d_in, const int* in_sizes, int n_in,
                              void* d_out, int out_size, void* d_ws, size_t ws_size,
                              hipStream_t stream) {
    const float* x  = (const float*)d_in[0];   // [8192, 256]
    const float* lm = (const float*)d_in[1];   // [2048, 256]
    float* out = (float*)d_out;

    char* ws = (char*)d_ws;
    unsigned short* xb = (unsigned short*)ws;                               // 4 MB
    unsigned short* lb = (unsigned short*)(ws + (size_t)B_ROWS*K_DIM*2);    // 1 MB
    float* gx2 = (float*)(ws + (size_t)B_ROWS*K_DIM*2 + (size_t)L_ROWS*K_DIM*2);
    float* gl2 = gx2 + B_ROWS;

    cvt_rows_kernel<<<(B_ROWS + L_ROWS)/4, 256, 0, stream>>>(x, lm, xb, lb, gx2, gl2);
    rbf_gemm_kernel<<<dim3(B_ROWS/128, L_ROWS/128), 256, 0, stream>>>(lb, xb, gl2, gx2, out);
}